// Round 2
// baseline (254.015 us; speedup 1.0000x reference)
//
#include <hip/hip_runtime.h>

// 16-segment breakpoints (module constants from the reference)
__device__ __constant__ float c_seg[16] = {
    0.0001f, 0.002f, 0.004f, 0.007f, 0.01f, 0.03f, 0.1f, 0.2f,
    0.3f,    1.0f,   2.0f,   4.0f,   8.0f,  16.0f, 64.0f, 1024.0f};

__device__ __forceinline__ float eval_seg(float x,
                                          const float* __restrict__ s_seg,
                                          const float* __restrict__ s_y0,
                                          const float* __restrict__ s_k) {
    // clamp into table range
    float xc = fminf(fmaxf(x, 0.0001f), 1024.0f);
    // searchsorted(side='left') - 1, clamped to [0,14]:
    // idx = count of seg[j] < xc over j=1..14
    int idx = 0;
    idx += (xc > 0.002f);
    idx += (xc > 0.004f);
    idx += (xc > 0.007f);
    idx += (xc > 0.01f);
    idx += (xc > 0.03f);
    idx += (xc > 0.1f);
    idx += (xc > 0.2f);
    idx += (xc > 0.3f);
    idx += (xc > 1.0f);
    idx += (xc > 2.0f);
    idx += (xc > 4.0f);
    idx += (xc > 8.0f);
    idx += (xc > 16.0f);
    idx += (xc > 64.0f);
    // 16 words sit in 16 distinct LDS banks -> per-lane gather is conflict-free
    float x0 = s_seg[idx];
    float y0 = s_y0[idx];
    float k  = s_k[idx];
    return fmaf(xc - x0, k, y0);
}

__device__ __forceinline__ float4 eval4(float4 v,
                                        const float* __restrict__ s_seg,
                                        const float* __restrict__ s_y0,
                                        const float* __restrict__ s_k) {
    float4 r;
    r.x = eval_seg(v.x, s_seg, s_y0, s_k);
    r.y = eval_seg(v.y, s_seg, s_y0, s_k);
    r.z = eval_seg(v.z, s_seg, s_y0, s_k);
    r.w = eval_seg(v.w, s_seg, s_y0, s_k);
    return r;
}

__global__ __launch_bounds__(256) void invsqrt16_kernel(
        const float4* __restrict__ x, float4* __restrict__ out, int n4) {
    __shared__ float s_seg[16];
    __shared__ float s_y0[16];
    __shared__ float s_k[16];
    if (threadIdx.x < 16) {
        int j = threadIdx.x;
        float s0 = c_seg[j];
        float s1 = c_seg[(j < 15) ? j + 1 : 15];
        float y0 = 1.0f / sqrtf(s0);
        float y1 = 1.0f / sqrtf(s1);
        s_seg[j] = s0;
        s_y0[j]  = y0;
        s_k[j]   = (j < 15) ? (y1 - y0) / (s1 - s0) : 0.0f;
    }
    __syncthreads();

    const int S = gridDim.x * blockDim.x;   // total threads
    int i = blockIdx.x * blockDim.x + threadIdx.x;

    // Main loop: 4 independent coalesced float4 loads in flight per thread
    for (; i + 3 * S < n4; i += 4 * S) {
        float4 v0 = x[i];
        float4 v1 = x[i + S];
        float4 v2 = x[i + 2 * S];
        float4 v3 = x[i + 3 * S];
        float4 r0 = eval4(v0, s_seg, s_y0, s_k);
        float4 r1 = eval4(v1, s_seg, s_y0, s_k);
        float4 r2 = eval4(v2, s_seg, s_y0, s_k);
        float4 r3 = eval4(v3, s_seg, s_y0, s_k);
        out[i]         = r0;
        out[i + S]     = r1;
        out[i + 2 * S] = r2;
        out[i + 3 * S] = r3;
    }
    // Tail
    for (; i < n4; i += S) {
        out[i] = eval4(x[i], s_seg, s_y0, s_k);
    }
}

extern "C" void kernel_launch(void* const* d_in, const int* in_sizes, int n_in,
                              void* d_out, int out_size, void* d_ws, size_t ws_size,
                              hipStream_t stream) {
    const float* x = (const float*)d_in[0];
    float* out = (float*)d_out;
    long long n = in_sizes[0];

    long long n4 = n >> 2;            // n = 32*4096*1024, divisible by 4
    int threads = 256;
    long long want = (n4 + threads - 1) / threads;
    int blocks = (int)((want < 2048) ? (want > 0 ? want : 1) : 2048);

    invsqrt16_kernel<<<blocks, threads, 0, stream>>>(
        (const float4*)x, (float4*)out, (int)n4);

    (void)d_ws; (void)ws_size; (void)n_in; (void)out_size;
}

// Round 4
// 200.309 us; speedup vs baseline: 1.2681x; 1.2681x over previous
//
#include <hip/hip_runtime.h>

typedef float f32x4 __attribute__((ext_vector_type(4)));

// 16-segment breakpoints (module constants from the reference)
__device__ __constant__ float c_seg[16] = {
    0.0001f, 0.002f, 0.004f, 0.007f, 0.01f, 0.03f, 0.1f, 0.2f,
    0.3f,    1.0f,   2.0f,   4.0f,   8.0f,  16.0f, 64.0f, 1024.0f};

__device__ __forceinline__ float eval_seg(float x,
                                          const float* __restrict__ s_seg,
                                          const float* __restrict__ s_y0,
                                          const float* __restrict__ s_k) {
    // clamp into table range
    float xc = fminf(fmaxf(x, 0.0001f), 1024.0f);
    // searchsorted(side='left') - 1, clamped to [0,14]:
    // idx = count of seg[j] < xc over j=1..14
    int idx = 0;
    idx += (xc > 0.002f);
    idx += (xc > 0.004f);
    idx += (xc > 0.007f);
    idx += (xc > 0.01f);
    idx += (xc > 0.03f);
    idx += (xc > 0.1f);
    idx += (xc > 0.2f);
    idx += (xc > 0.3f);
    idx += (xc > 1.0f);
    idx += (xc > 2.0f);
    idx += (xc > 4.0f);
    idx += (xc > 8.0f);
    idx += (xc > 16.0f);
    idx += (xc > 64.0f);
    // 16 words sit in 16 distinct LDS banks -> per-lane gather is conflict-free
    float x0 = s_seg[idx];
    float y0 = s_y0[idx];
    float k  = s_k[idx];
    return fmaf(xc - x0, k, y0);
}

__global__ __launch_bounds__(256) void invsqrt16_kernel(
        const f32x4* __restrict__ x, f32x4* __restrict__ out, int n4) {
    __shared__ float s_seg[16];
    __shared__ float s_y0[16];
    __shared__ float s_k[16];
    if (threadIdx.x < 16) {
        int j = threadIdx.x;
        float s0 = c_seg[j];
        float s1 = c_seg[(j < 15) ? j + 1 : 15];
        float y0 = 1.0f / sqrtf(s0);
        float y1 = 1.0f / sqrtf(s1);
        s_seg[j] = s0;
        s_y0[j]  = y0;
        s_k[j]   = (j < 15) ? (y1 - y0) / (s1 - s0) : 0.0f;
    }
    __syncthreads();

    int stride = gridDim.x * blockDim.x;
    for (int i = blockIdx.x * blockDim.x + threadIdx.x; i < n4; i += stride) {
        // nontemporal: pure streaming data, zero reuse -> don't allocate in cache
        f32x4 v = __builtin_nontemporal_load(&x[i]);
        f32x4 r;
        r.x = eval_seg(v.x, s_seg, s_y0, s_k);
        r.y = eval_seg(v.y, s_seg, s_y0, s_k);
        r.z = eval_seg(v.z, s_seg, s_y0, s_k);
        r.w = eval_seg(v.w, s_seg, s_y0, s_k);
        __builtin_nontemporal_store(r, &out[i]);
    }
}

extern "C" void kernel_launch(void* const* d_in, const int* in_sizes, int n_in,
                              void* d_out, int out_size, void* d_ws, size_t ws_size,
                              hipStream_t stream) {
    const float* x = (const float*)d_in[0];
    float* out = (float*)d_out;
    long long n = in_sizes[0];

    long long n4 = n >> 2;            // n = 32*4096*1024, divisible by 4
    int threads = 256;
    long long want = (n4 + threads - 1) / threads;
    int blocks = (int)((want < 2048) ? (want > 0 ? want : 1) : 2048);

    invsqrt16_kernel<<<blocks, threads, 0, stream>>>(
        (const f32x4*)x, (f32x4*)out, (int)n4);

    (void)d_ws; (void)ws_size; (void)n_in; (void)out_size;
}